// Round 6
// baseline (547.496 us; speedup 1.0000x reference)
//
#include <hip/hip_runtime.h>

#define B_  4
#define S_  2048
#define D_  1024
#define F_  4096
#define E_  8
#define C_  320
#define MPAD_ 1280         // per-expert padded rows; max real = 4*320 = 1280
#define NT_ (B_*S_)        // 8192 tokens

typedef short bf16x8 __attribute__((ext_vector_type(8)));
typedef float f32x4  __attribute__((ext_vector_type(4)));

using gptr_t = const __attribute__((address_space(1))) void*;
using lptr_t = __attribute__((address_space(3))) void*;

__device__ static inline void gll16(const void* g, void* l) {
    __builtin_amdgcn_global_load_lds((gptr_t)g, (lptr_t)l, 16, 0, 0);
}

// fp32 -> bf16 round-to-nearest-even (finite inputs only)
__device__ static inline unsigned short f2b(float f) {
    unsigned int u = __float_as_uint(f);
    u += 0x7fffu + ((u >> 16) & 1u);
    return (unsigned short)(u >> 16);
}

// ---------------- fused fp32->bf16 convert + transpose ----------------
__global__ __launch_bounds__(256) void k_convT(const float* __restrict__ in,
                                               unsigned short* __restrict__ out,
                                               int R, int Cc) {
    __shared__ unsigned short ld[64][66];
    int e = blockIdx.z;
    const float* src = in + (size_t)e * R * Cc;
    unsigned short* dst = out + (size_t)e * R * Cc;
    int c0 = blockIdx.x * 64, r0 = blockIdx.y * 64;
    int t = threadIdx.x;

    int rr = t >> 4;
    int cg = t & 15;
#pragma unroll
    for (int p = 0; p < 4; p++) {
        int row = p * 16 + rr;
        float4 v = *(const float4*)(src + (size_t)(r0 + row) * Cc + c0 + cg * 4);
        ld[cg * 4 + 0][row] = f2b(v.x);
        ld[cg * 4 + 1][row] = f2b(v.y);
        ld[cg * 4 + 2][row] = f2b(v.z);
        ld[cg * 4 + 3][row] = f2b(v.w);
    }
    __syncthreads();

    int cc = t >> 3;
    int rg = t & 7;
#pragma unroll
    for (int p = 0; p < 2; p++) {
        int col = p * 32 + cc;
        const unsigned* lp = (const unsigned*)&ld[col][rg * 8];
        uint4 w;
        w.x = lp[0]; w.y = lp[1]; w.z = lp[2]; w.w = lp[3];
        *(uint4*)(dst + (size_t)(c0 + col) * R + r0 + rg * 8) = w;
    }
}

// ---------------- router: logits + softmax top-1 ----------------
__global__ __launch_bounds__(256) void k_router(const float* __restrict__ hs,
                                                const float* __restrict__ gw,
                                                float* __restrict__ logits,
                                                int* __restrict__ eidx,
                                                float* __restrict__ tp) {
    int tok  = (int)((blockIdx.x * 256 + threadIdx.x) >> 6);
    int lane = threadIdx.x & 63;
    const float* x = hs + (size_t)tok * D_;
    double acc[E_];
#pragma unroll
    for (int e = 0; e < E_; e++) acc[e] = 0.0;
    for (int i = 0; i < 16; i++) {
        float xv = x[lane + 64 * i];
#pragma unroll
        for (int e = 0; e < E_; e++)
            acc[e] += (double)xv * (double)gw[e * D_ + lane + 64 * i];
    }
#pragma unroll
    for (int e = 0; e < E_; e++) {
#pragma unroll
        for (int off = 32; off > 0; off >>= 1)
            acc[e] += __shfl_xor(acc[e], off, 64);
    }
    if (lane == 0) {
        float l[E_];
        float mx = -1e30f; int am = 0;
#pragma unroll
        for (int e = 0; e < E_; e++) {
            l[e] = (float)acc[e];
            if (l[e] > mx) { mx = l[e]; am = e; }
        }
        float se = 0.f;
#pragma unroll
        for (int e = 0; e < E_; e++) se += __expf(l[e] - mx);
        tp[tok]   = 1.0f / se;
        eidx[tok] = am;
#pragma unroll
        for (int e = 0; e < E_; e++) logits[(size_t)tok * E_ + e] = l[e];
    }
}

// ---------------- capacity scan: slot assignment per batch ----------------
__global__ __launch_bounds__(256) void k_scan(const int* __restrict__ eidx,
                                              int* __restrict__ slot,
                                              int* __restrict__ tok_list,
                                              int* __restrict__ counts,
                                              float* __restrict__ eif) {
    int b = blockIdx.x;
    __shared__ int cCnt[32][E_];
    __shared__ int cBase[32][E_];
    int t = threadIdx.x, wv = t >> 6, lane = t & 63;
    const int* eb = eidx + b * S_;
    for (int c = wv; c < 32; c += 4) {
        int e = eb[c * 64 + lane];
#pragma unroll
        for (int x = 0; x < E_; x++) {
            unsigned long long m = __ballot(e == x);
            if (lane == 0) cCnt[c][x] = __popcll(m);
        }
    }
    __syncthreads();
    if (t < E_) {
        int s = 0;
        for (int c = 0; c < 32; c++) { cBase[c][t] = s; s += cCnt[c][t]; }
        counts[b * E_ + t] = s;
    }
    __syncthreads();
    for (int c = wv; c < 32; c += 4) {
        int s_tok = c * 64 + lane;
        int e = eb[s_tok];
        unsigned long long lowmask = (1ull << lane) - 1ull;
        int rank = 0;
#pragma unroll
        for (int x = 0; x < E_; x++) {
            unsigned long long m = __ballot(e == x);
            if (x == e) rank = __popcll(m & lowmask);
        }
        int pos = cBase[c][e] + rank;
        int assigned = (pos < C_);
        slot[b * S_ + s_tok] = assigned ? pos : C_;
        if (assigned) tok_list[(b * E_ + e) * C_ + pos] = s_tok;
        eif[b * S_ + s_tok] = assigned ? (float)e : 0.0f;
    }
}

// ---------------- cross-batch expert bases ----------------
__global__ void k_base(const int* __restrict__ counts,
                       int* __restrict__ ebase,
                       int* __restrict__ nE) {
    int e = threadIdx.x;
    if (e < E_) {
        int s = 0;
#pragma unroll
        for (int b = 0; b < B_; b++) {
            ebase[b * E_ + e] = s;
            s += min(counts[b * E_ + e], C_);
        }
        nE[e] = s;
    }
}

// ---------------- dispatch: gather tokens -> bf16 Xd[e][MPAD_][D_] ----------------
__global__ __launch_bounds__(256) void k_dispatch(const float* __restrict__ hs,
                                                  const int* __restrict__ tlB,
                                                  const int* __restrict__ ebase,
                                                  const int* __restrict__ nE,
                                                  int* __restrict__ tlG,
                                                  unsigned short* __restrict__ Xd) {
    int w    = (int)((blockIdx.x * 256 + threadIdx.x) >> 6);  // one wave per row
    int lane = threadIdx.x & 63;
    int e = w / MPAD_, r = w - e * MPAD_;
    unsigned short* drow = Xd + ((size_t)e * MPAD_ + r) * D_;
    if (r < nE[e]) {
        int b = 0;
#pragma unroll
        for (int bb = 1; bb < B_; bb++) if (r >= ebase[bb * E_ + e]) b = bb;
        int pos = r - ebase[b * E_ + e];
        int ts  = tlB[(b * E_ + e) * C_ + pos];
        if (lane == 0) tlG[e * MPAD_ + r] = b * S_ + ts;
        const float* src = hs + ((size_t)b * S_ + ts) * D_;
#pragma unroll
        for (int i = 0; i < 2; i++) {
            int c0 = (lane + 64 * i) * 8;
            float4 v0 = *(const float4*)(src + c0);
            float4 v1 = *(const float4*)(src + c0 + 4);
            uint4 pk;
            pk.x = (unsigned)f2b(v0.x) | ((unsigned)f2b(v0.y) << 16);
            pk.y = (unsigned)f2b(v0.z) | ((unsigned)f2b(v0.w) << 16);
            pk.z = (unsigned)f2b(v1.x) | ((unsigned)f2b(v1.y) << 16);
            pk.w = (unsigned)f2b(v1.z) | ((unsigned)f2b(v1.w) << 16);
            *(uint4*)(drow + c0) = pk;
        }
    } else {
        uint4 zz = {0u, 0u, 0u, 0u};
#pragma unroll
        for (int i = 0; i < 2; i++)
            *(uint4*)(drow + (lane + 64 * i) * 8) = zz;
    }
}

// ---------------- 128x128xBK64 m97-style GEMM core (multi-block TLP) ----------------
// 256 threads = 4 waves (2M x 2N), wave tile 64x64, acc 4x4 f32x4.
// LDS: 32 KB single buffer (A 16KB + B 16KB).
// XOR swizzle: 16B-slot ^= (row&7) -> conflict-free ds_read_b128 (verified r5).
template<int LDK, int KT>
__device__ __forceinline__ void gemm_core(const unsigned short* __restrict__ Ab,
                                          const unsigned short* __restrict__ Bb,
                                          char* sm, f32x4 (&acc)[4][4]) {
    const int t    = threadIdx.x;      // 0..255
    const int lane = t & 63;
    const int wv   = t >> 6;           // 0..3
    const int wm   = wv >> 1;          // 0..1
    const int wn   = wv & 1;           // 0..1

    const int sr  = t >> 3;            // 0..31
    const int scs = (t & 7) ^ (sr & 7);
    const unsigned short* aS = Ab + (size_t)sr * LDK + scs * 8;
    const unsigned short* bS = Bb + (size_t)sr * LDK + scs * 8;
    char* ldsA = sm;
    char* ldsB = sm + 16384;
    const int wvoff = wv * 1024;

    const int rl  = lane & 15;
    const int sw  = lane & 7;
    const int kg  = lane >> 4;                 // 0..3
    const int sx0 = ((kg    ) ^ sw) << 4;      // kk=0, slots 0..3
    const int sx1 = ((kg + 4) ^ sw) << 4;      // kk=1, slots 4..7
    const int aro = (wm * 64 + rl) * 128;
    const int bro = (wn * 64 + rl) * 128;

#pragma unroll 1
    for (int kt = 0; kt < KT; ++kt) {
        __syncthreads();               // WAR: prior tile's frag reads complete
        const unsigned short* aP = aS + kt * 64;
        const unsigned short* bP = bS + kt * 64;
#pragma unroll
        for (int j = 0; j < 4; j++) gll16(aP + (size_t)(j * 32) * LDK, ldsA + j * 4096 + wvoff);
#pragma unroll
        for (int j = 0; j < 4; j++) gll16(bP + (size_t)(j * 32) * LDK, ldsB + j * 4096 + wvoff);
        __syncthreads();               // drains vmcnt -> staged data visible

        bf16x8 a[4], b[4];
#pragma unroll
        for (int i = 0; i < 4; i++) a[i] = *(const bf16x8*)(ldsA + aro + i * 2048 + sx0);
#pragma unroll
        for (int j = 0; j < 4; j++) b[j] = *(const bf16x8*)(ldsB + bro + j * 2048 + sx0);
#pragma unroll
        for (int i = 0; i < 4; i++)
#pragma unroll
            for (int j = 0; j < 4; j++)
                acc[i][j] = __builtin_amdgcn_mfma_f32_16x16x32_bf16(a[i], b[j], acc[i][j], 0, 0, 0);
#pragma unroll
        for (int i = 0; i < 4; i++) a[i] = *(const bf16x8*)(ldsA + aro + i * 2048 + sx1);
#pragma unroll
        for (int j = 0; j < 4; j++) b[j] = *(const bf16x8*)(ldsB + bro + j * 2048 + sx1);
#pragma unroll
        for (int i = 0; i < 4; i++)
#pragma unroll
            for (int j = 0; j < 4; j++)
                acc[i][j] = __builtin_amdgcn_mfma_f32_16x16x32_bf16(a[i], b[j], acc[i][j], 0, 0, 0);
    }
}

// ---------------- 64x128xBK64 GEMM core for grid-starved ffn2 ----------------
// 256 threads = 4 waves (1M x 4N), wave tile 64x32, acc 4x2 f32x4.
// LDS: 24 KB single buffer (A 8KB + B 16KB) -> 6 blocks/CU capacity.
// Same XOR swizzle as gemm_core.
template<int LDK, int KT>
__device__ __forceinline__ void gemm_core64(const unsigned short* __restrict__ Ab,
                                            const unsigned short* __restrict__ Bb,
                                            char* sm, f32x4 (&acc)[4][2]) {
    const int t    = threadIdx.x;      // 0..255
    const int lane = t & 63;
    const int wv   = t >> 6;           // 0..3 -> N quadrant
    const int wn   = wv;

    const int sr  = t >> 3;            // 0..31
    const int scs = (t & 7) ^ (sr & 7);
    const unsigned short* aS = Ab + (size_t)sr * LDK + scs * 8;
    const unsigned short* bS = Bb + (size_t)sr * LDK + scs * 8;
    char* ldsA = sm;                   // 8 KB: 64 rows x 128B
    char* ldsB = sm + 8192;            // 16 KB: 128 rows x 128B
    const int wvoff = wv * 1024;

    const int rl  = lane & 15;
    const int sw  = lane & 7;
    const int kg  = lane >> 4;                 // 0..3
    const int sx0 = ((kg    ) ^ sw) << 4;      // kk=0
    const int sx1 = ((kg + 4) ^ sw) << 4;      // kk=1
    const int aro = rl * 128;                  // A rows i*16 + rl
    const int bro = (wn * 32 + rl) * 128;      // B cols wn*32 + j*16 + rl

#pragma unroll 1
    for (int kt = 0; kt < KT; ++kt) {
        __syncthreads();
        const unsigned short* aP = aS + kt * 64;
        const unsigned short* bP = bS + kt * 64;
#pragma unroll
        for (int j = 0; j < 2; j++) gll16(aP + (size_t)(j * 32) * LDK, ldsA + j * 4096 + wvoff);
#pragma unroll
        for (int j = 0; j < 4; j++) gll16(bP + (size_t)(j * 32) * LDK, ldsB + j * 4096 + wvoff);
        __syncthreads();

        bf16x8 a[4], b[2];
#pragma unroll
        for (int i = 0; i < 4; i++) a[i] = *(const bf16x8*)(ldsA + aro + i * 2048 + sx0);
#pragma unroll
        for (int j = 0; j < 2; j++) b[j] = *(const bf16x8*)(ldsB + bro + j * 2048 + sx0);
#pragma unroll
        for (int i = 0; i < 4; i++)
#pragma unroll
            for (int j = 0; j < 2; j++)
                acc[i][j] = __builtin_amdgcn_mfma_f32_16x16x32_bf16(a[i], b[j], acc[i][j], 0, 0, 0);
#pragma unroll
        for (int i = 0; i < 4; i++) a[i] = *(const bf16x8*)(ldsA + aro + i * 2048 + sx1);
#pragma unroll
        for (int j = 0; j < 2; j++) b[j] = *(const bf16x8*)(ldsB + bro + j * 2048 + sx1);
#pragma unroll
        for (int i = 0; i < 4; i++)
#pragma unroll
            for (int j = 0; j < 2; j++)
                acc[i][j] = __builtin_amdgcn_mfma_f32_16x16x32_bf16(a[i], b[j], acc[i][j], 0, 0, 0);
    }
}

// ---------------- GEMM1: h = silu(Xd @ w1t^T), bf16 out ----------------
__global__ __launch_bounds__(256, 4) void k_ffn1(const unsigned short* __restrict__ Xd,
                                                 const unsigned short* __restrict__ w1t,
                                                 const int* __restrict__ nE,
                                                 unsigned short* __restrict__ h) {
    __shared__ __align__(16) char sm[32768];
    int id  = blockIdx.x;          // 2560 blocks; id&7 -> XCD -> expert
    int e   = id & 7;
    int rem = id >> 3;             // 0..319
    int mt  = rem % 10;            // mt-inner: consecutive blocks share B panel
    int nt  = rem / 10;            // 0..31
    int m0  = mt * 128;
    if (m0 >= nE[e]) return;
    int n0  = nt * 128;

    f32x4 acc[4][4];
    f32x4 z = {0.f, 0.f, 0.f, 0.f};
#pragma unroll
    for (int i = 0; i < 4; i++)
#pragma unroll
        for (int j = 0; j < 4; j++) acc[i][j] = z;

    const unsigned short* Ab = Xd  + ((size_t)e * MPAD_ + m0) * D_;
    const unsigned short* Bb = w1t + ((size_t)e * F_    + n0) * D_;
    gemm_core<D_, D_ / 64>(Ab, Bb, sm, acc);

    int lane = threadIdx.x & 63, wv = threadIdx.x >> 6, wm = wv >> 1, wn = wv & 1;
    unsigned short* hb = h + (size_t)e * MPAD_ * F_;
    int rb = m0 + wm * 64 + ((lane >> 4) << 2);
    int cb = n0 + wn * 64 + (lane & 15);
#pragma unroll
    for (int i = 0; i < 4; i++)
#pragma unroll
        for (int r = 0; r < 4; r++) {
            unsigned short* hr = hb + (size_t)(rb + i * 16 + r) * F_ + cb;
#pragma unroll
            for (int j = 0; j < 4; j++) {
                float v = acc[i][j][r];
                v = v / (1.0f + __expf(-v));    // silu
                hr[j * 16] = f2b(v);
            }
        }
}

// ---------------- GEMM2: y = h @ w2t^T, scale by top_prob, scatter ----------------
__global__ __launch_bounds__(256, 6) void k_ffn2(const unsigned short* __restrict__ h,
                                                 const unsigned short* __restrict__ w2t,
                                                 const int* __restrict__ nE,
                                                 const int* __restrict__ tlG,
                                                 const float* __restrict__ tp,
                                                 float* __restrict__ out) {
    __shared__ __align__(16) char sm[24576];
    int id  = blockIdx.x;          // 1280 blocks; id&7 -> XCD -> expert
    int e   = id & 7;
    int rem = id >> 3;             // 0..159
    int mt  = rem % 20;            // mt-inner: consecutive blocks share B panel
    int nt  = rem / 20;            // 0..7
    int m0  = mt * 64;
    int n   = nE[e];
    if (m0 >= n) return;
    int n0  = nt * 128;

    f32x4 acc[4][2];
    f32x4 z = {0.f, 0.f, 0.f, 0.f};
#pragma unroll
    for (int i = 0; i < 4; i++)
#pragma unroll
        for (int j = 0; j < 2; j++) acc[i][j] = z;

    const unsigned short* Ab = h   + ((size_t)e * MPAD_ + m0) * F_;
    const unsigned short* Bb = w2t + ((size_t)e * D_    + n0) * F_;
    gemm_core64<F_, F_ / 64>(Ab, Bb, sm, acc);

    int lane = threadIdx.x & 63, wn = threadIdx.x >> 6;
    const int* tl = tlG + e * MPAD_;
    int rb = m0 + ((lane >> 4) << 2);
    int cb = n0 + wn * 32 + (lane & 15);
#pragma unroll
    for (int i = 0; i < 4; i++)
#pragma unroll
        for (int r = 0; r < 4; r++) {
            int row = rb + i * 16 + r;
            if (row < n) {
                int gt = tl[row];                       // b*S + token
                float sc = tp[gt];
                float* orow = out + (size_t)gt * D_ + cb;
#pragma unroll
                for (int j = 0; j < 2; j++)
                    orow[j * 16] = sc * acc[i][j][r];
            }
        }
}

// ---------------- passthrough for dropped tokens ----------------
__global__ __launch_bounds__(256) void k_pass(const float* __restrict__ hs,
                                              const int* __restrict__ slot,
                                              const float* __restrict__ tp,
                                              float* __restrict__ out) {
    int tok  = (int)((blockIdx.x * 256 + threadIdx.x) >> 6);
    int lane = threadIdx.x & 63;
    if (slot[tok] < C_) return;
    float sc = tp[tok];
    const float* src = hs + (size_t)tok * D_;
    float* dst = out + (size_t)tok * D_;
#pragma unroll
    for (int i = 0; i < 4; i++) {
        float4 v = *(const float4*)(src + (lane + 64 * i) * 4);
        v.x *= sc; v.y *= sc; v.z *= sc; v.w *= sc;
        *(float4*)(dst + (lane + 64 * i) * 4) = v;
    }
}

extern "C" void kernel_launch(void* const* d_in, const int* in_sizes, int n_in,
                              void* d_out, int out_size, void* d_ws, size_t ws_size,
                              hipStream_t stream) {
    const float* hs = (const float*)d_in[0];
    const float* gw = (const float*)d_in[1];
    const float* w1 = (const float*)d_in[2];
    const float* w2 = (const float*)d_in[3];

    float* out    = (float*)d_out;                       // [B,S,D] fp32
    float* logits = out + (size_t)NT_ * D_;              // [B,S,E] fp32
    float* eif    = logits + (size_t)NT_ * E_;           // [B,S]

    char* ws = (char*)d_ws;
    int*            eidx   = (int*)(ws + 0);
    int*            slot   = (int*)(ws + 65536);
    float*          tp     = (float*)(ws + 131072);
    int*            tlB    = (int*)(ws + 196608);        // per-batch tok lists [B*E*C]
    int*            tlG    = (int*)(ws + 237568);        // global tok list [E*MPAD_]
    int*            counts = (int*)(ws + 278528);        // [B*E]
    int*            ebase  = (int*)(ws + 278784);        // [B*E]
    int*            nE     = (int*)(ws + 279040);        // [E]
    unsigned short* Xd     = (unsigned short*)(ws + 327680);        // [E][MPAD_][D] bf16, 21 MB
    unsigned short* w1t    = (unsigned short*)(ws + 33554432ull);   // [E][F][D] bf16, 64 MB
    unsigned short* w2t    = (unsigned short*)(ws + 100663296ull);  // [E][D][F] bf16, 64 MB
    unsigned short* hbuf   = (unsigned short*)(ws + 167772160ull);  // [E][MPAD_][F] bf16, 80 MB

    dim3 blk(256);
    k_convT<<<dim3(F_ / 64, D_ / 64, E_), blk, 0, stream>>>(w1, w1t, D_, F_);
    k_convT<<<dim3(D_ / 64, F_ / 64, E_), blk, 0, stream>>>(w2, w2t, F_, D_);
    k_router<<<dim3(NT_ / 4), blk, 0, stream>>>(hs, gw, logits, eidx, tp);
    k_scan<<<dim3(B_), blk, 0, stream>>>(eidx, slot, tlB, counts, eif);
    k_base<<<dim3(1), dim3(64), 0, stream>>>(counts, ebase, nE);
    k_dispatch<<<dim3(E_ * MPAD_ / 4), blk, 0, stream>>>(hs, tlB, ebase, nE, tlG, Xd);
    k_ffn1<<<dim3(2560), blk, 0, stream>>>(Xd, w1t, nE, hbuf);
    k_ffn2<<<dim3(1280), blk, 0, stream>>>(hbuf, w2t, nE, tlG, tp, out);
    k_pass<<<dim3(NT_ / 4), blk, 0, stream>>>(hs, slot, tp, out);
}

// Round 7
// 533.191 us; speedup vs baseline: 1.0268x; 1.0268x over previous
//
#include <hip/hip_runtime.h>

#define B_  4
#define S_  2048
#define D_  1024
#define F_  4096
#define E_  8
#define C_  320
#define MPAD_ 1280         // per-expert padded rows; max real = 4*320 = 1280
#define NT_ (B_*S_)        // 8192 tokens

typedef short bf16x8 __attribute__((ext_vector_type(8)));
typedef float f32x4  __attribute__((ext_vector_type(4)));

using gptr_t = const __attribute__((address_space(1))) void*;
using lptr_t = __attribute__((address_space(3))) void*;

__device__ static inline void gll16(const void* g, void* l) {
    __builtin_amdgcn_global_load_lds((gptr_t)g, (lptr_t)l, 16, 0, 0);
}

// fp32 -> bf16 round-to-nearest-even (finite inputs only)
__device__ static inline unsigned short f2b(float f) {
    unsigned int u = __float_as_uint(f);
    u += 0x7fffu + ((u >> 16) & 1u);
    return (unsigned short)(u >> 16);
}

// ---------------- mega: convT(w1) + convT(w2) + router in one launch ----------------
// blocks [0,8192): w1 [D][F] fp32 -> w1t [F][D] bf16
// blocks [8192,16384): w2 [F][D] fp32 -> w2t [D][F] bf16
// blocks [16384,18432): router (4 token-waves per block)
__global__ __launch_bounds__(256) void k_mega(const float* __restrict__ w1,
                                              const float* __restrict__ w2,
                                              unsigned short* __restrict__ w1t,
                                              unsigned short* __restrict__ w2t,
                                              const float* __restrict__ hs,
                                              const float* __restrict__ gw,
                                              float* __restrict__ logits,
                                              int* __restrict__ eidx,
                                              float* __restrict__ tp) {
    __shared__ unsigned short ld[64][66];   // convT transpose staging
    int bid = blockIdx.x;
    int t = threadIdx.x;

    if (bid < 16384) {
        // ------- convT path -------
        const float* src; unsigned short* dst; int R, Cc, c0, r0;
        if (bid < 8192) {
            int e = bid >> 10, rem = bid & 1023;
            R = D_; Cc = F_;
            c0 = (rem & 63) * 64; r0 = (rem >> 6) * 64;
            src = w1 + (size_t)e * R * Cc; dst = w1t + (size_t)e * R * Cc;
        } else {
            int b2 = bid - 8192;
            int e = b2 >> 10, rem = b2 & 1023;
            R = F_; Cc = D_;
            c0 = (rem & 15) * 64; r0 = (rem >> 4) * 64;
            src = w2 + (size_t)e * R * Cc; dst = w2t + (size_t)e * R * Cc;
        }
        int rr = t >> 4, cg = t & 15;
#pragma unroll
        for (int p = 0; p < 4; p++) {
            int row = p * 16 + rr;
            float4 v = *(const float4*)(src + (size_t)(r0 + row) * Cc + c0 + cg * 4);
            ld[cg * 4 + 0][row] = f2b(v.x);
            ld[cg * 4 + 1][row] = f2b(v.y);
            ld[cg * 4 + 2][row] = f2b(v.z);
            ld[cg * 4 + 3][row] = f2b(v.w);
        }
        __syncthreads();
        int cc = t >> 3, rg = t & 7;
#pragma unroll
        for (int p = 0; p < 2; p++) {
            int col = p * 32 + cc;
            const unsigned* lp = (const unsigned*)&ld[col][rg * 8];
            uint4 w;
            w.x = lp[0]; w.y = lp[1]; w.z = lp[2]; w.w = lp[3];
            *(uint4*)(dst + (size_t)(c0 + col) * R + r0 + rg * 8) = w;
        }
        return;
    }

    // ------- router path -------
    int rb = bid - 16384;                       // 0..2047
    int tok  = (int)((rb * 256 + t) >> 6);
    int lane = t & 63;
    const float* x = hs + (size_t)tok * D_;
    double acc[E_];
#pragma unroll
    for (int e = 0; e < E_; e++) acc[e] = 0.0;
    for (int i = 0; i < 16; i++) {
        float xv = x[lane + 64 * i];
#pragma unroll
        for (int e = 0; e < E_; e++)
            acc[e] += (double)xv * (double)gw[e * D_ + lane + 64 * i];
    }
#pragma unroll
    for (int e = 0; e < E_; e++) {
#pragma unroll
        for (int off = 32; off > 0; off >>= 1)
            acc[e] += __shfl_xor(acc[e], off, 64);
    }
    if (lane == 0) {
        float l[E_];
        float mx = -1e30f; int am = 0;
#pragma unroll
        for (int e = 0; e < E_; e++) {
            l[e] = (float)acc[e];
            if (l[e] > mx) { mx = l[e]; am = e; }   // strict > : first max wins
        }
        float se = 0.f;
#pragma unroll
        for (int e = 0; e < E_; e++) se += __expf(l[e] - mx);
        tp[tok]   = 1.0f / se;
        eidx[tok] = am;
#pragma unroll
        for (int e = 0; e < E_; e++) logits[(size_t)tok * E_ + e] = l[e];
    }
}

// ---------------- capacity scan: slot assignment per batch ----------------
__global__ __launch_bounds__(256) void k_scan(const int* __restrict__ eidx,
                                              int* __restrict__ slot,
                                              int* __restrict__ tok_list,
                                              int* __restrict__ counts,
                                              float* __restrict__ eif) {
    int b = blockIdx.x;
    __shared__ int cCnt[32][E_];
    __shared__ int cBase[32][E_];
    int t = threadIdx.x, wv = t >> 6, lane = t & 63;
    const int* eb = eidx + b * S_;
    for (int c = wv; c < 32; c += 4) {
        int e = eb[c * 64 + lane];
#pragma unroll
        for (int x = 0; x < E_; x++) {
            unsigned long long m = __ballot(e == x);
            if (lane == 0) cCnt[c][x] = __popcll(m);
        }
    }
    __syncthreads();
    if (t < E_) {
        int s = 0;
        for (int c = 0; c < 32; c++) { cBase[c][t] = s; s += cCnt[c][t]; }
        counts[b * E_ + t] = s;
    }
    __syncthreads();
    for (int c = wv; c < 32; c += 4) {
        int s_tok = c * 64 + lane;
        int e = eb[s_tok];
        unsigned long long lowmask = (1ull << lane) - 1ull;
        int rank = 0;
#pragma unroll
        for (int x = 0; x < E_; x++) {
            unsigned long long m = __ballot(e == x);
            if (x == e) rank = __popcll(m & lowmask);
        }
        int pos = cBase[c][e] + rank;
        int assigned = (pos < C_);
        slot[b * S_ + s_tok] = assigned ? pos : C_;
        if (assigned) tok_list[(b * E_ + e) * C_ + pos] = s_tok;
        eif[b * S_ + s_tok] = assigned ? (float)e : 0.0f;
    }
}

// ---------------- dispatch: gather tokens -> bf16 Xd[e][MPAD_][D_] (inline base) ----------------
__global__ __launch_bounds__(256) void k_dispatch(const float* __restrict__ hs,
                                                  const int* __restrict__ tlB,
                                                  const int* __restrict__ counts,
                                                  int* __restrict__ nE,
                                                  int* __restrict__ tlG,
                                                  unsigned short* __restrict__ Xd) {
    int w    = (int)((blockIdx.x * 256 + threadIdx.x) >> 6);  // one wave per row
    int lane = threadIdx.x & 63;
    int e = w / MPAD_, r = w - e * MPAD_;

    // inline cross-batch base computation from counts (32 ints, L2-hot)
    int ebv[B_]; int s = 0;
#pragma unroll
    for (int bb = 0; bb < B_; bb++) {
        ebv[bb] = s;
        s += min(counts[bb * E_ + e], C_);
    }
    int ne = s;
    if (r == 0 && lane == 0) nE[e] = ne;      // exactly one wave per expert

    unsigned short* drow = Xd + ((size_t)e * MPAD_ + r) * D_;
    if (r < ne) {
        int b = 0;
#pragma unroll
        for (int bb = 1; bb < B_; bb++) if (r >= ebv[bb]) b = bb;
        int pos = r - ebv[b];
        int ts  = tlB[(b * E_ + e) * C_ + pos];
        if (lane == 0) tlG[e * MPAD_ + r] = b * S_ + ts;
        const float* src = hs + ((size_t)b * S_ + ts) * D_;
#pragma unroll
        for (int i = 0; i < 2; i++) {
            int c0 = (lane + 64 * i) * 8;
            float4 v0 = *(const float4*)(src + c0);
            float4 v1 = *(const float4*)(src + c0 + 4);
            uint4 pk;
            pk.x = (unsigned)f2b(v0.x) | ((unsigned)f2b(v0.y) << 16);
            pk.y = (unsigned)f2b(v0.z) | ((unsigned)f2b(v0.w) << 16);
            pk.z = (unsigned)f2b(v1.x) | ((unsigned)f2b(v1.y) << 16);
            pk.w = (unsigned)f2b(v1.z) | ((unsigned)f2b(v1.w) << 16);
            *(uint4*)(drow + c0) = pk;
        }
    } else {
        uint4 zz = {0u, 0u, 0u, 0u};
#pragma unroll
        for (int i = 0; i < 2; i++)
            *(uint4*)(drow + (lane + 64 * i) * 8) = zz;
    }
}

// ---------------- 128x128xBK64 m97-style GEMM core (multi-block TLP) ----------------
// 256 threads = 4 waves (2M x 2N), wave tile 64x64, acc 4x4 f32x4.
// LDS: 32 KB single buffer (A 16KB + B 16KB) -> 5 blocks/CU capacity.
// XOR swizzle: 16B-slot ^= (row&7) -> conflict-free ds_read_b128 (verified r5: 0 conflicts).
template<int LDK, int KT>
__device__ __forceinline__ void gemm_core(const unsigned short* __restrict__ Ab,
                                          const unsigned short* __restrict__ Bb,
                                          char* sm, f32x4 (&acc)[4][4]) {
    const int t    = threadIdx.x;      // 0..255
    const int lane = t & 63;
    const int wv   = t >> 6;           // 0..3
    const int wm   = wv >> 1;          // 0..1
    const int wn   = wv & 1;           // 0..1

    const int sr  = t >> 3;            // 0..31
    const int scs = (t & 7) ^ (sr & 7);
    const unsigned short* aS = Ab + (size_t)sr * LDK + scs * 8;
    const unsigned short* bS = Bb + (size_t)sr * LDK + scs * 8;
    char* ldsA = sm;
    char* ldsB = sm + 16384;
    const int wvoff = wv * 1024;

    const int rl  = lane & 15;
    const int sw  = lane & 7;
    const int kg  = lane >> 4;                 // 0..3
    const int sx0 = ((kg    ) ^ sw) << 4;      // kk=0, slots 0..3
    const int sx1 = ((kg + 4) ^ sw) << 4;      // kk=1, slots 4..7
    const int aro = (wm * 64 + rl) * 128;
    const int bro = (wn * 64 + rl) * 128;

#pragma unroll 1
    for (int kt = 0; kt < KT; ++kt) {
        __syncthreads();               // WAR: prior tile's frag reads complete
        const unsigned short* aP = aS + kt * 64;
        const unsigned short* bP = bS + kt * 64;
#pragma unroll
        for (int j = 0; j < 4; j++) gll16(aP + (size_t)(j * 32) * LDK, ldsA + j * 4096 + wvoff);
#pragma unroll
        for (int j = 0; j < 4; j++) gll16(bP + (size_t)(j * 32) * LDK, ldsB + j * 4096 + wvoff);
        __syncthreads();               // drains vmcnt -> staged data visible

        bf16x8 a[4], b[4];
#pragma unroll
        for (int i = 0; i < 4; i++) a[i] = *(const bf16x8*)(ldsA + aro + i * 2048 + sx0);
#pragma unroll
        for (int j = 0; j < 4; j++) b[j] = *(const bf16x8*)(ldsB + bro + j * 2048 + sx0);
#pragma unroll
        for (int i = 0; i < 4; i++)
#pragma unroll
            for (int j = 0; j < 4; j++)
                acc[i][j] = __builtin_amdgcn_mfma_f32_16x16x32_bf16(a[i], b[j], acc[i][j], 0, 0, 0);
#pragma unroll
        for (int i = 0; i < 4; i++) a[i] = *(const bf16x8*)(ldsA + aro + i * 2048 + sx1);
#pragma unroll
        for (int j = 0; j < 4; j++) b[j] = *(const bf16x8*)(ldsB + bro + j * 2048 + sx1);
#pragma unroll
        for (int i = 0; i < 4; i++)
#pragma unroll
            for (int j = 0; j < 4; j++)
                acc[i][j] = __builtin_amdgcn_mfma_f32_16x16x32_bf16(a[i], b[j], acc[i][j], 0, 0, 0);
    }
}

// ---------------- GEMM1: h = silu(Xd @ w1t^T), bf16 out ----------------
__global__ __launch_bounds__(256, 5) void k_ffn1(const unsigned short* __restrict__ Xd,
                                                 const unsigned short* __restrict__ w1t,
                                                 const int* __restrict__ nE,
                                                 unsigned short* __restrict__ h) {
    __shared__ __align__(16) char sm[32768];
    int id  = blockIdx.x;          // 2560 blocks; id&7 -> XCD -> expert
    int e   = id & 7;
    int rem = id >> 3;             // 0..319
    int mt  = rem % 10;            // mt-inner: consecutive blocks share B panel
    int nt  = rem / 10;            // 0..31
    int m0  = mt * 128;
    if (m0 >= nE[e]) return;
    int n0  = nt * 128;

    f32x4 acc[4][4];
    f32x4 z = {0.f, 0.f, 0.f, 0.f};
#pragma unroll
    for (int i = 0; i < 4; i++)
#pragma unroll
        for (int j = 0; j < 4; j++) acc[i][j] = z;

    const unsigned short* Ab = Xd  + ((size_t)e * MPAD_ + m0) * D_;
    const unsigned short* Bb = w1t + ((size_t)e * F_    + n0) * D_;
    gemm_core<D_, D_ / 64>(Ab, Bb, sm, acc);

    int lane = threadIdx.x & 63, wv = threadIdx.x >> 6, wm = wv >> 1, wn = wv & 1;
    unsigned short* hb = h + (size_t)e * MPAD_ * F_;
    int rb = m0 + wm * 64 + ((lane >> 4) << 2);
    int cb = n0 + wn * 64 + (lane & 15);
#pragma unroll
    for (int i = 0; i < 4; i++)
#pragma unroll
        for (int r = 0; r < 4; r++) {
            unsigned short* hr = hb + (size_t)(rb + i * 16 + r) * F_ + cb;
#pragma unroll
            for (int j = 0; j < 4; j++) {
                float v = acc[i][j][r];
                v = v / (1.0f + __expf(-v));    // silu
                hr[j * 16] = f2b(v);
            }
        }
}

// ---------------- GEMM2: y = h @ w2t^T + fused dropped-token passthrough ----------------
// blocks [0,640): GEMM tiles (round-5 proven config, 107us)
// blocks [640,768): passthrough for dropped tokens (disjoint output rows)
__global__ __launch_bounds__(256, 5) void k_ffn2(const unsigned short* __restrict__ h,
                                                 const unsigned short* __restrict__ w2t,
                                                 const int* __restrict__ nE,
                                                 const int* __restrict__ tlG,
                                                 const float* __restrict__ tp,
                                                 const int* __restrict__ slot,
                                                 const float* __restrict__ hs,
                                                 float* __restrict__ out) {
    __shared__ __align__(16) char sm[32768];
    int id  = blockIdx.x;

    if (id >= 640) {                   // ------- passthrough region -------
        int pb = id - 640;             // 0..127, 64 tokens each
        int wv = threadIdx.x >> 6, lane = threadIdx.x & 63;
        int base = pb * 64 + wv * 16;
        for (int k = 0; k < 16; k++) {
            int tok = base + k;
            if (slot[tok] < C_) continue;      // assigned: written by GEMM blocks
            float sc = tp[tok];
            const float* src = hs + (size_t)tok * D_;
            float* dst = out + (size_t)tok * D_;
#pragma unroll
            for (int i = 0; i < 4; i++) {
                float4 v = *(const float4*)(src + (lane + 64 * i) * 4);
                v.x *= sc; v.y *= sc; v.z *= sc; v.w *= sc;
                *(float4*)(dst + (lane + 64 * i) * 4) = v;
            }
        }
        return;
    }

    int e   = id & 7;                  // XCD -> expert
    int rem = id >> 3;                 // 0..79
    int mt  = rem % 10;                // mt-inner: consecutive blocks share B panel
    int nt  = rem / 10;                // 0..7
    int m0  = mt * 128;
    int n   = nE[e];
    if (m0 >= n) return;
    int n0  = nt * 128;

    f32x4 acc[4][4];
    f32x4 z = {0.f, 0.f, 0.f, 0.f};
#pragma unroll
    for (int i = 0; i < 4; i++)
#pragma unroll
        for (int j = 0; j < 4; j++) acc[i][j] = z;

    const unsigned short* Ab = h   + ((size_t)e * MPAD_ + m0) * F_;
    const unsigned short* Bb = w2t + ((size_t)e * D_    + n0) * F_;
    gemm_core<F_, F_ / 64>(Ab, Bb, sm, acc);

    int lane = threadIdx.x & 63, wv = threadIdx.x >> 6, wm = wv >> 1, wn = wv & 1;
    const int* tl = tlG + e * MPAD_;
    int rb = m0 + wm * 64 + ((lane >> 4) << 2);
    int cb = n0 + wn * 64 + (lane & 15);
#pragma unroll
    for (int i = 0; i < 4; i++)
#pragma unroll
        for (int r = 0; r < 4; r++) {
            int row = rb + i * 16 + r;
            if (row < n) {
                int gt = tl[row];                       // b*S + token
                float sc = tp[gt];
                float* orow = out + (size_t)gt * D_ + cb;
#pragma unroll
                for (int j = 0; j < 4; j++)
                    orow[j * 16] = sc * acc[i][j][r];
            }
        }
}

extern "C" void kernel_launch(void* const* d_in, const int* in_sizes, int n_in,
                              void* d_out, int out_size, void* d_ws, size_t ws_size,
                              hipStream_t stream) {
    const float* hs = (const float*)d_in[0];
    const float* gw = (const float*)d_in[1];
    const float* w1 = (const float*)d_in[2];
    const float* w2 = (const float*)d_in[3];

    float* out    = (float*)d_out;                       // [B,S,D] fp32
    float* logits = out + (size_t)NT_ * D_;              // [B,S,E] fp32
    float* eif    = logits + (size_t)NT_ * E_;           // [B,S]

    char* ws = (char*)d_ws;
    int*            eidx   = (int*)(ws + 0);
    int*            slot   = (int*)(ws + 65536);
    float*          tp     = (float*)(ws + 131072);
    int*            tlB    = (int*)(ws + 196608);        // per-batch tok lists [B*E*C]
    int*            tlG    = (int*)(ws + 237568);        // global tok list [E*MPAD_]
    int*            counts = (int*)(ws + 278528);        // [B*E]
    int*            nE     = (int*)(ws + 279040);        // [E]
    unsigned short* Xd     = (unsigned short*)(ws + 327680);        // [E][MPAD_][D] bf16, 21 MB
    unsigned short* w1t    = (unsigned short*)(ws + 33554432ull);   // [E][F][D] bf16, 64 MB
    unsigned short* w2t    = (unsigned short*)(ws + 100663296ull);  // [E][D][F] bf16, 64 MB
    unsigned short* hbuf   = (unsigned short*)(ws + 167772160ull);  // [E][MPAD_][F] bf16, 80 MB

    dim3 blk(256);
    k_mega<<<dim3(18432), blk, 0, stream>>>(w1, w2, w1t, w2t, hs, gw, logits, eidx, tp);
    k_scan<<<dim3(B_), blk, 0, stream>>>(eidx, slot, tlB, counts, eif);
    k_dispatch<<<dim3(E_ * MPAD_ / 4), blk, 0, stream>>>(hs, tlB, counts, nE, tlG, Xd);
    k_ffn1<<<dim3(2560), blk, 0, stream>>>(Xd, w1t, nE, hbuf);
    k_ffn2<<<dim3(768), blk, 0, stream>>>(hbuf, w2t, nE, tlG, tp, slot, hs, out);
}